// Round 16
// baseline (105.866 us; speedup 1.0000x reference)
//
#include <hip/hip_runtime.h>

// EdgewiseEnergySum:
//   out[n] = 0.125 * sum_{e : center(e)==n} edge_eng[e] * scales[sp[center(e)], sp[neighbor(e)]]
//
// R1: 6.4M global atomics -> 344 us.  R2: counting-sort -> 162 us.
// R10: LDS-staged K1 -> 89 us.  R11: global alloc in K1 path -> +19 us (lesson).
// R12: padding zeros -> acc[0] same-address serialization (lesson).
// R13/14/15: K2 skip-branch variants all 42-51 us with EVERYTHING idle.
//      Diagnosis: the per-quad branch forces s_waitcnt vmcnt(0) before the
//      test -> exactly ONE load in flight per thread -> L2-latency-serial.
//      (Evidence: CAP 80->64 cut reads but raised time; branch-free R8 K2
//      was fastest. Atomic volume is trivial: 99K wave-ops total.)
// R16: branch-free K2, unconditional atomics (striped-identity padding from
//      R15 makes them exact: +0.0 to acc[w&1023], bank-spread), manual
//      unroll-by-2 with both uint4 loads issued before any atomic.

#define BUCKET_SHIFT 10
#define BUCKET_NODES 1024
#define STAGE_NB     104              // LDS sizing; actual nb = 98
#define CAP          64               // per-(chunk,bucket): mean 41.9 + 3.4 sigma
#define STR          68               // stride: %4==0 (b128-aligned), spreads banks
#define K1_THREADS   512
#define CHUNK        4096             // 512 threads * 8 edges
#define KS           8                // K2 blocks per bucket
#define K2_THREADS   512
#define MAX_SP_WORDS 6272             // 2-bit species, 16/word (25 KB)
#define OVF_CAP      65536

// ---------------- K0: pack species 2-bit + zero overflow counter ----------
__global__ void k0_pack(const int* __restrict__ species,
                        unsigned int* __restrict__ packed,
                        int* __restrict__ ovf_cnt,
                        int n_nodes, int n_words)
{
    const int w = blockIdx.x * blockDim.x + threadIdx.x;
    if (w == 0) *ovf_cnt = 0;
    if (w >= n_words) return;
    const int base = w * 16;
    unsigned int v = 0;
    if (base + 16 <= n_nodes) {
#pragma unroll
        for (int q = 0; q < 4; ++q) {
            const int4 s4 = *(const int4*)(species + base + 4 * q);
            v |= (unsigned int)(s4.x & 3) << (8 * q + 0);
            v |= (unsigned int)(s4.y & 3) << (8 * q + 2);
            v |= (unsigned int)(s4.z & 3) << (8 * q + 4);
            v |= (unsigned int)(s4.w & 3) << (8 * q + 6);
        }
    } else {
        const int m = n_nodes - base;
        for (int j = 0; j < m; ++j)
            v |= (unsigned int)(species[base + j] & 3) << (2 * j);
    }
    packed[w] = v;
}

// ---------------- K1: LDS-staged scatter, b128 copy-out -------------------
__global__ void __launch_bounds__(K1_THREADS)
k1_scatter(const float* __restrict__ edge_eng,
           const int*   __restrict__ edge_center,
           const int*   __restrict__ edge_neighbor,
           const unsigned int* __restrict__ sp_packed,
           const float* __restrict__ scales,
           unsigned int* __restrict__ recs,     // [nb][n_chunks][CAP]
           int2*         __restrict__ ovf,
           int*          __restrict__ ovf_cnt,
           int n_edges, int n_chunks, int nb, int n_sp_words)
{
    __shared__ unsigned int s_sp[MAX_SP_WORDS];    // 25.1 KB
    __shared__ unsigned int stage[STAGE_NB * STR]; // 27.6 KB
    __shared__ float s_scale[16];
    __shared__ int cursor[STAGE_NB];
    // total ~53.2 KB -> 3 blocks/CU

    const int tid = threadIdx.x;
    if (tid < 16) s_scale[tid] = scales[tid] * 0.125f;   // fold 1/sqrt(64)
    for (int i = tid; i < n_sp_words; i += K1_THREADS) s_sp[i] = sp_packed[i];
    {   // striped-identity fill: word w -> w&1023 (value=+0.0, index striped)
        uint4* sz = (uint4*)stage;
        const int nz = nb * (STR / 4);
        for (int i = tid; i < nz; i += K1_THREADS) {
            const unsigned int base = ((unsigned)i << 2) & 1023u;
            sz[i] = make_uint4(base, base + 1, base + 2, base + 3);
        }
    }
    for (int b = tid; b < nb; b += K1_THREADS) cursor[b] = 0;
    __syncthreads();

    const int cid = blockIdx.x;
    const int lo  = cid * CHUNK;

    // ---- Load this thread's 8 edges ONCE into registers ------------------
    int4   c4[2];
    int4   n4[2];
    float4 e4[2];
    const bool full = ((n_edges & 3) == 0) && (lo + CHUNK <= n_edges);
    if (full) {
#pragma unroll
        for (int k = 0; k < 2; ++k) {
            const int idx = lo + 4 * tid + (4 * K1_THREADS) * k;
            c4[k] = *(const int4*)  (edge_center   + idx);
            n4[k] = *(const int4*)  (edge_neighbor + idx);
            e4[k] = *(const float4*)(edge_eng      + idx);
        }
    } else {
#pragma unroll
        for (int k = 0; k < 2; ++k) {
            const int idx = lo + 4 * tid + (4 * K1_THREADS) * k;
            int*   cp = (int*)  &c4[k];
            int*   np = (int*)  &n4[k];
            float* ep = (float*)&e4[k];
#pragma unroll
            for (int j = 0; j < 4; ++j) {
                const int i = idx + j;
                if (i < n_edges) { cp[j] = edge_center[i]; np[j] = edge_neighbor[i]; ep[j] = edge_eng[i]; }
                else             { cp[j] = -1; np[j] = 0; ep[j] = 0.0f; }
            }
        }
    }

    // ---- Scatter 4B records into per-bucket LDS lists --------------------
#define SP(n) ((s_sp[(unsigned)(n) >> 4] >> (((n) & 15) << 1)) & 3)
#pragma unroll
    for (int k = 0; k < 2; ++k) {
        const int*   cp = (const int*)  &c4[k];
        const int*   np = (const int*)  &n4[k];
        const float* ep = (const float*)&e4[k];
#pragma unroll
        for (int j = 0; j < 4; ++j) {
            const int c = cp[j];
            if (c < 0) continue;
            const int   b = c >> BUCKET_SHIFT;
            const float v = ep[j] * s_scale[(SP(c) << 2) | SP(np[j])];
            const unsigned int rec = (__float_as_uint(v) & 0xFFFFFC00u)
                                   | ((unsigned int)c & (BUCKET_NODES - 1));
            const int r = atomicAdd(&cursor[b], 1);          // LDS atomic
            if (r < CAP) {
                stage[b * STR + r] = rec;                    // LDS write
            } else {                                         // rare: spill
                const int oi = atomicAdd(ovf_cnt, 1);
                if (oi < OVF_CAP) ovf[oi] = make_int2(c, __float_as_int(v));
            }
        }
    }
#undef SP
    __syncthreads();

    // ---- b128 copy-out: 4 regions per wave-instr -------------------------
    const int wav  = tid >> 6;
    const int lane = tid & 63;
    const int ngroups = (nb + 3) >> 2;
    for (int g = wav; g < ngroups; g += (K1_THREADS / 64)) {
        const int b = 4 * g + (lane >> 4);
        if (b < nb) {
            const uint4 v = *(const uint4*)&stage[b * STR + (lane & 15) * 4];
            unsigned int* dst = recs + ((size_t)b * n_chunks + cid) * CAP + (lane & 15) * 4;
            *(uint4*)dst = v;
        }
    }
}

// ---------------- K2: branch-free dense streaming accumulation ------------
#define AT4(r)                                                                  \
    atomicAdd(&acc[(r).x & (BUCKET_NODES - 1)], __uint_as_float((r).x & 0xFFFFFC00u)); \
    atomicAdd(&acc[(r).y & (BUCKET_NODES - 1)], __uint_as_float((r).y & 0xFFFFFC00u)); \
    atomicAdd(&acc[(r).z & (BUCKET_NODES - 1)], __uint_as_float((r).z & 0xFFFFFC00u)); \
    atomicAdd(&acc[(r).w & (BUCKET_NODES - 1)], __uint_as_float((r).w & 0xFFFFFC00u));

__global__ void __launch_bounds__(K2_THREADS)
k2_accumulate(const unsigned int* __restrict__ recs,
              float* __restrict__ partials,    // [nb*KS][1024]
              int n_chunks)
{
    __shared__ float acc[BUCKET_NODES];
    const int b   = blockIdx.x / KS;
    const int s   = blockIdx.x % KS;
    const int tid = threadIdx.x;

    for (int i = tid; i < BUCKET_NODES; i += K2_THREADS) acc[i] = 0.0f;
    __syncthreads();

    const unsigned int* p = recs + (size_t)b * n_chunks * CAP;
    const int W   = n_chunks * CAP;              // words per bucket (mult of 64)
    const int per = W / KS;                      // contiguous per-block range
    const int lo  = s * per;
    const int hi  = lo + per;

    // Unroll-by-2: both loads issued before any atomic (2 loads in flight,
    // no branch between load and use -> compiler can pipeline).
    int i = lo + tid * 4;
    for (; i + 4 + K2_THREADS * 4 <= hi; i += K2_THREADS * 8) {
        const uint4 ra = *(const uint4*)(p + i);
        const uint4 rb = *(const uint4*)(p + i + K2_THREADS * 4);
        AT4(ra);
        AT4(rb);
    }
    for (; i + 4 <= hi; i += K2_THREADS * 4) {
        const uint4 ra = *(const uint4*)(p + i);
        AT4(ra);
    }
    __syncthreads();

    float* dst = partials + (size_t)blockIdx.x * BUCKET_NODES;
    for (int i2 = tid; i2 < BUCKET_NODES; i2 += K2_THREADS) dst[i2] = acc[i2];
}
#undef AT4

// ---------------- K3: reduce KS partials, plain store ---------------------
__global__ void k3_reduce(const float* __restrict__ partials,
                          float*       __restrict__ out, int n_nodes)
{
    const int n = blockIdx.x * blockDim.x + threadIdx.x;
    if (n >= n_nodes) return;
    const int b     = n >> BUCKET_SHIFT;
    const int local = n & (BUCKET_NODES - 1);
    const float* p  = partials + (size_t)b * KS * BUCKET_NODES + local;
    float sum = 0.0f;
#pragma unroll
    for (int i = 0; i < KS; ++i) sum += p[i * BUCKET_NODES];
    out[n] = sum;
}

// ---------------- K4: drain overflow spill ---------------------------------
__global__ void k4_overflow(const int2* __restrict__ ovf,
                            const int*  __restrict__ ovf_cnt,
                            float*      __restrict__ out)
{
    const int n = min(*ovf_cnt, OVF_CAP);
    const int i0 = blockIdx.x * blockDim.x + threadIdx.x;
    for (int i = i0; i < n; i += gridDim.x * blockDim.x)
        atomicAdd(&out[ovf[i].x], __int_as_float(ovf[i].y));
}

// ---------------- Fallback: atomic kernel (if ws too small) ---------------
__global__ void fallback_atomic_kernel(const float* __restrict__ edge_eng,
                                       const int*   __restrict__ edge_center,
                                       const int*   __restrict__ edge_neighbor,
                                       const int*   __restrict__ species,
                                       const float* __restrict__ scales,
                                       float*       __restrict__ out, int n_edges)
{
    __shared__ float s_scale[16];
    if (threadIdx.x < 16) s_scale[threadIdx.x] = scales[threadIdx.x] * 0.125f;
    __syncthreads();
    const int stride = gridDim.x * blockDim.x;
    for (int i = blockIdx.x * blockDim.x + threadIdx.x; i < n_edges; i += stride) {
        const int c  = edge_center[i];
        const int cs = species[c];
        const int ns = species[edge_neighbor[i]];
        atomicAdd(&out[c], edge_eng[i] * s_scale[(cs << 2) | ns]);
    }
}

extern "C" void kernel_launch(void* const* d_in, const int* in_sizes, int n_in,
                              void* d_out, int out_size, void* d_ws, size_t ws_size,
                              hipStream_t stream) {
    const float* edge_eng   = (const float*)d_in[0];
    const int*   edge_index = (const int*)  d_in[1];
    const int*   species    = (const int*)  d_in[2];
    const float* scales     = (const float*)d_in[3];
    float*       out        = (float*)      d_out;

    const int n_edges = in_sizes[1] / 2;
    const int n_nodes = in_sizes[2];
    const int* edge_center   = edge_index;
    const int* edge_neighbor = edge_index + n_edges;

    const int nb       = (n_nodes + BUCKET_NODES - 1) >> BUCKET_SHIFT;
    const int n_words  = (n_nodes + 15) / 16;
    const int n_chunks = (n_edges + CHUNK - 1) / CHUNK;

    // ws layout: [ovf_cnt: 4096 pad][packed][recs][partials][ovf]
    const size_t off_ovfcnt   = 0;
    const size_t off_packed   = 4096;
    const size_t off_recs     = (off_packed + (size_t)n_words * 4 + 255) & ~(size_t)255;
    const size_t off_partials = off_recs + (size_t)nb * n_chunks * CAP * 4;
    const size_t off_ovf      = off_partials + (size_t)nb * KS * BUCKET_NODES * 4;
    const size_t needed       = off_ovf + (size_t)OVF_CAP * sizeof(int2);

    if (nb > STAGE_NB || n_words > MAX_SP_WORDS || ws_size < needed) {
        hipMemsetAsync(d_out, 0, (size_t)out_size * sizeof(float), stream);
        int grid = (n_edges + 255) / 256;
        if (grid > 2048) grid = 2048;
        fallback_atomic_kernel<<<grid, 256, 0, stream>>>(
            edge_eng, edge_center, edge_neighbor, species, scales, out, n_edges);
        return;
    }

    int*          ovf_cnt  = (int*)         ((char*)d_ws + off_ovfcnt);
    unsigned int* packed   = (unsigned int*)((char*)d_ws + off_packed);
    unsigned int* recs     = (unsigned int*)((char*)d_ws + off_recs);
    float*        partials = (float*)       ((char*)d_ws + off_partials);
    int2*         ovf      = (int2*)        ((char*)d_ws + off_ovf);

    k0_pack<<<(n_words + 255) / 256, 256, 0, stream>>>(
        species, packed, ovf_cnt, n_nodes, n_words);

    k1_scatter<<<n_chunks, K1_THREADS, 0, stream>>>(
        edge_eng, edge_center, edge_neighbor, packed, scales,
        recs, ovf, ovf_cnt, n_edges, n_chunks, nb, n_words);

    k2_accumulate<<<nb * KS, K2_THREADS, 0, stream>>>(recs, partials, n_chunks);

    k3_reduce<<<(n_nodes + 255) / 256, 256, 0, stream>>>(partials, out, n_nodes);

    k4_overflow<<<4, 256, 0, stream>>>(ovf, ovf_cnt, out);
}

// Round 17
// 81.924 us; speedup vs baseline: 1.2922x; 1.2922x over previous
//
#include <hip/hip_runtime.h>

// EdgewiseEnergySum:
//   out[n] = 0.125 * sum_{e : center(e)==n} edge_eng[e] * scales[sp[center(e)], sp[neighbor(e)]]
//
// R1: 6.4M global atomics -> 344 us.  R2: counting-sort -> 162 us.
// R10: LDS-staged K1 -> 89 us.  R11: global alloc in K1 path +19 us (lesson).
// R12: padding zeros all hit acc[0] -> same-address LDS-atomic serialization.
// R13: 5-branch zero-skip, CAP=80 -> 86 us (best; K1 42.5 + K2 42).
// R14: CAP=64 diet -> K1 34 but K2 49.  R15: 1-branch -> K2 50.8.
// R16: branch-free unconditional -> K2 66.4. Conclusion: K2 cost tracks
//      EXECUTED LDS-atomic count (LDS f32 RMW is expensive); R13's skip-many
//      variant is measured-best. My cycle model under-predicts latency-bound
//      kernels ~3x; assemble measured-best hybrid instead of theorizing.
// R17: K2 = R13 verbatim (CAP=80, KS=16, 5-branch skip).
//      K1 = R13 structure + R14's cheap mechanics: uint4 stage-zero and
//      b128 copy-out (STR 81->84 for alignment; 3 regions/wave-instr).

#define BUCKET_SHIFT 10
#define BUCKET_NODES 1024
#define STAGE_NB     104              // LDS sizing; actual nb = 98
#define CAP          80               // per-(chunk,bucket): mean 41.9 + ~5.9 sigma
#define STR          84               // stride: %4==0 (b128), 84%32=20 spreads banks
#define K1_THREADS   512
#define CHUNK        4096             // 512 threads * 8 edges
#define KS           16               // K2 blocks per bucket
#define K2_THREADS   512
#define MAX_SP_WORDS 6272             // 2-bit species, 16/word (25 KB)
#define OVF_CAP      65536

// ---------------- K0: pack species 2-bit + zero overflow counter ----------
__global__ void k0_pack(const int* __restrict__ species,
                        unsigned int* __restrict__ packed,
                        int* __restrict__ ovf_cnt,
                        int n_nodes, int n_words)
{
    const int w = blockIdx.x * blockDim.x + threadIdx.x;
    if (w == 0) *ovf_cnt = 0;
    if (w >= n_words) return;
    const int base = w * 16;
    unsigned int v = 0;
    if (base + 16 <= n_nodes) {
#pragma unroll
        for (int q = 0; q < 4; ++q) {
            const int4 s4 = *(const int4*)(species + base + 4 * q);
            v |= (unsigned int)(s4.x & 3) << (8 * q + 0);
            v |= (unsigned int)(s4.y & 3) << (8 * q + 2);
            v |= (unsigned int)(s4.z & 3) << (8 * q + 4);
            v |= (unsigned int)(s4.w & 3) << (8 * q + 6);
        }
    } else {
        const int m = n_nodes - base;
        for (int j = 0; j < m; ++j)
            v |= (unsigned int)(species[base + j] & 3) << (2 * j);
    }
    packed[w] = v;
}

// ---------------- K1: LDS-staged scatter, b128 copy-out -------------------
__global__ void __launch_bounds__(K1_THREADS)
k1_scatter(const float* __restrict__ edge_eng,
           const int*   __restrict__ edge_center,
           const int*   __restrict__ edge_neighbor,
           const unsigned int* __restrict__ sp_packed,
           const float* __restrict__ scales,
           unsigned int* __restrict__ recs,     // [nb][n_chunks][CAP]
           int2*         __restrict__ ovf,
           int*          __restrict__ ovf_cnt,
           int n_edges, int n_chunks, int nb, int n_sp_words)
{
    __shared__ unsigned int s_sp[MAX_SP_WORDS];    // 25.1 KB
    __shared__ unsigned int stage[STAGE_NB * STR]; // 32.9 KB (nb=98 used)
    __shared__ float s_scale[16];
    __shared__ int cursor[STAGE_NB];
    // total ~58.5 KB -> 2 blocks/CU (R13 parity)

    const int tid = threadIdx.x;
    if (tid < 16) s_scale[tid] = scales[tid] * 0.125f;   // fold 1/sqrt(64)
    for (int i = tid; i < n_sp_words; i += K1_THREADS) s_sp[i] = sp_packed[i];
    {   // uint4 zero-fill of the stage (R14 mechanic)
        uint4* sz = (uint4*)stage;
        const int nz = nb * (STR / 4);
        const uint4 z = make_uint4(0u, 0u, 0u, 0u);
        for (int i = tid; i < nz; i += K1_THREADS) sz[i] = z;
    }
    for (int b = tid; b < nb; b += K1_THREADS) cursor[b] = 0;
    __syncthreads();

    const int cid = blockIdx.x;
    const int lo  = cid * CHUNK;

    // ---- Load this thread's 8 edges ONCE into registers ------------------
    int4   c4[2];
    int4   n4[2];
    float4 e4[2];
    const bool full = ((n_edges & 3) == 0) && (lo + CHUNK <= n_edges);
    if (full) {
#pragma unroll
        for (int k = 0; k < 2; ++k) {
            const int idx = lo + 4 * tid + (4 * K1_THREADS) * k;
            c4[k] = *(const int4*)  (edge_center   + idx);
            n4[k] = *(const int4*)  (edge_neighbor + idx);
            e4[k] = *(const float4*)(edge_eng      + idx);
        }
    } else {
#pragma unroll
        for (int k = 0; k < 2; ++k) {
            const int idx = lo + 4 * tid + (4 * K1_THREADS) * k;
            int*   cp = (int*)  &c4[k];
            int*   np = (int*)  &n4[k];
            float* ep = (float*)&e4[k];
#pragma unroll
            for (int j = 0; j < 4; ++j) {
                const int i = idx + j;
                if (i < n_edges) { cp[j] = edge_center[i]; np[j] = edge_neighbor[i]; ep[j] = edge_eng[i]; }
                else             { cp[j] = -1; np[j] = 0; ep[j] = 0.0f; }
            }
        }
    }

    // ---- Scatter 4B records into per-bucket LDS lists --------------------
#define SP(n) ((s_sp[(unsigned)(n) >> 4] >> (((n) & 15) << 1)) & 3)
#pragma unroll
    for (int k = 0; k < 2; ++k) {
        const int*   cp = (const int*)  &c4[k];
        const int*   np = (const int*)  &n4[k];
        const float* ep = (const float*)&e4[k];
#pragma unroll
        for (int j = 0; j < 4; ++j) {
            const int c = cp[j];
            if (c < 0) continue;
            const int   b = c >> BUCKET_SHIFT;
            const float v = ep[j] * s_scale[(SP(c) << 2) | SP(np[j])];
            const unsigned int rec = (__float_as_uint(v) & 0xFFFFFC00u)
                                   | ((unsigned int)c & (BUCKET_NODES - 1));
            const int r = atomicAdd(&cursor[b], 1);          // LDS atomic
            if (r < CAP) {
                stage[b * STR + r] = rec;                    // LDS write
            } else {                                         // rare: spill
                const int oi = atomicAdd(ovf_cnt, 1);
                if (oi < OVF_CAP) ovf[oi] = make_int2(c, __float_as_int(v));
            }
        }
    }
#undef SP
    __syncthreads();

    // ---- b128 copy-out: 3 regions per wave-instr (20 quads each) ---------
    // lanes 0..59: region r_local = lane/20, quad q = lane%20
    const int wav  = tid >> 6;
    const int lane = tid & 63;
    const int ngroups = (nb + 2) / 3;
    for (int g = wav; g < ngroups; g += (K1_THREADS / 64)) {
        const int b = 3 * g + lane / 20;
        const int q = lane % 20;
        if (lane < 60 && b < nb) {
            const uint4 v = *(const uint4*)&stage[b * STR + q * 4];
            unsigned int* dst = recs + ((size_t)b * n_chunks + cid) * CAP + q * 4;
            *(uint4*)dst = v;
        }
    }
}

// ---------------- K2: R13-verbatim dense streaming accumulation -----------
__global__ void __launch_bounds__(K2_THREADS)
k2_accumulate(const unsigned int* __restrict__ recs,
              float* __restrict__ partials,    // [nb*KS][1024]
              int n_chunks)
{
    __shared__ float acc[BUCKET_NODES];
    const int b   = blockIdx.x / KS;
    const int s   = blockIdx.x % KS;
    const int tid = threadIdx.x;

    for (int i = tid; i < BUCKET_NODES; i += K2_THREADS) acc[i] = 0.0f;
    __syncthreads();

    const unsigned int* p = recs + (size_t)b * n_chunks * CAP;
    const int total = n_chunks * CAP;            // multiple of 4

    for (int i = (s * K2_THREADS + tid) * 4; i + 4 <= total; i += KS * K2_THREADS * 4) {
        const uint4 r = *(const uint4*)(p + i);
        // Skip padding zeros (R12 lesson); executed-atomic count is the cost
        // (R13 vs R16), so skip as many as possible.
        if (r.x | r.y | r.z | r.w) {
            if (r.x) atomicAdd(&acc[r.x & (BUCKET_NODES - 1)], __uint_as_float(r.x & 0xFFFFFC00u));
            if (r.y) atomicAdd(&acc[r.y & (BUCKET_NODES - 1)], __uint_as_float(r.y & 0xFFFFFC00u));
            if (r.z) atomicAdd(&acc[r.z & (BUCKET_NODES - 1)], __uint_as_float(r.z & 0xFFFFFC00u));
            if (r.w) atomicAdd(&acc[r.w & (BUCKET_NODES - 1)], __uint_as_float(r.w & 0xFFFFFC00u));
        }
    }
    __syncthreads();

    float* dst = partials + (size_t)blockIdx.x * BUCKET_NODES;
    for (int i = tid; i < BUCKET_NODES; i += K2_THREADS) dst[i] = acc[i];
}

// ---------------- K3: reduce KS partials, plain store ---------------------
__global__ void k3_reduce(const float* __restrict__ partials,
                          float*       __restrict__ out, int n_nodes)
{
    const int n = blockIdx.x * blockDim.x + threadIdx.x;
    if (n >= n_nodes) return;
    const int b     = n >> BUCKET_SHIFT;
    const int local = n & (BUCKET_NODES - 1);
    const float* p  = partials + (size_t)b * KS * BUCKET_NODES + local;
    float sum = 0.0f;
#pragma unroll
    for (int i = 0; i < KS; ++i) sum += p[i * BUCKET_NODES];
    out[n] = sum;
}

// ---------------- K4: drain overflow spill ---------------------------------
__global__ void k4_overflow(const int2* __restrict__ ovf,
                            const int*  __restrict__ ovf_cnt,
                            float*      __restrict__ out)
{
    const int n = min(*ovf_cnt, OVF_CAP);
    const int i0 = blockIdx.x * blockDim.x + threadIdx.x;
    for (int i = i0; i < n; i += gridDim.x * blockDim.x)
        atomicAdd(&out[ovf[i].x], __int_as_float(ovf[i].y));
}

// ---------------- Fallback: atomic kernel (if ws too small) ---------------
__global__ void fallback_atomic_kernel(const float* __restrict__ edge_eng,
                                       const int*   __restrict__ edge_center,
                                       const int*   __restrict__ edge_neighbor,
                                       const int*   __restrict__ species,
                                       const float* __restrict__ scales,
                                       float*       __restrict__ out, int n_edges)
{
    __shared__ float s_scale[16];
    if (threadIdx.x < 16) s_scale[threadIdx.x] = scales[threadIdx.x] * 0.125f;
    __syncthreads();
    const int stride = gridDim.x * blockDim.x;
    for (int i = blockIdx.x * blockDim.x + threadIdx.x; i < n_edges; i += stride) {
        const int c  = edge_center[i];
        const int cs = species[c];
        const int ns = species[edge_neighbor[i]];
        atomicAdd(&out[c], edge_eng[i] * s_scale[(cs << 2) | ns]);
    }
}

extern "C" void kernel_launch(void* const* d_in, const int* in_sizes, int n_in,
                              void* d_out, int out_size, void* d_ws, size_t ws_size,
                              hipStream_t stream) {
    const float* edge_eng   = (const float*)d_in[0];
    const int*   edge_index = (const int*)  d_in[1];
    const int*   species    = (const int*)  d_in[2];
    const float* scales     = (const float*)d_in[3];
    float*       out        = (float*)      d_out;

    const int n_edges = in_sizes[1] / 2;
    const int n_nodes = in_sizes[2];
    const int* edge_center   = edge_index;
    const int* edge_neighbor = edge_index + n_edges;

    const int nb       = (n_nodes + BUCKET_NODES - 1) >> BUCKET_SHIFT;
    const int n_words  = (n_nodes + 15) / 16;
    const int n_chunks = (n_edges + CHUNK - 1) / CHUNK;

    // ws layout: [ovf_cnt: 4096 pad][packed][recs][partials][ovf]
    const size_t off_ovfcnt   = 0;
    const size_t off_packed   = 4096;
    const size_t off_recs     = (off_packed + (size_t)n_words * 4 + 255) & ~(size_t)255;
    const size_t off_partials = off_recs + (size_t)nb * n_chunks * CAP * 4;
    const size_t off_ovf      = off_partials + (size_t)nb * KS * BUCKET_NODES * 4;
    const size_t needed       = off_ovf + (size_t)OVF_CAP * sizeof(int2);

    if (nb > STAGE_NB || n_words > MAX_SP_WORDS || ws_size < needed) {
        hipMemsetAsync(d_out, 0, (size_t)out_size * sizeof(float), stream);
        int grid = (n_edges + 255) / 256;
        if (grid > 2048) grid = 2048;
        fallback_atomic_kernel<<<grid, 256, 0, stream>>>(
            edge_eng, edge_center, edge_neighbor, species, scales, out, n_edges);
        return;
    }

    int*          ovf_cnt  = (int*)         ((char*)d_ws + off_ovfcnt);
    unsigned int* packed   = (unsigned int*)((char*)d_ws + off_packed);
    unsigned int* recs     = (unsigned int*)((char*)d_ws + off_recs);
    float*        partials = (float*)       ((char*)d_ws + off_partials);
    int2*         ovf      = (int2*)        ((char*)d_ws + off_ovf);

    k0_pack<<<(n_words + 255) / 256, 256, 0, stream>>>(
        species, packed, ovf_cnt, n_nodes, n_words);

    k1_scatter<<<n_chunks, K1_THREADS, 0, stream>>>(
        edge_eng, edge_center, edge_neighbor, packed, scales,
        recs, ovf, ovf_cnt, n_edges, n_chunks, nb, n_words);

    k2_accumulate<<<nb * KS, K2_THREADS, 0, stream>>>(recs, partials, n_chunks);

    k3_reduce<<<(n_nodes + 255) / 256, 256, 0, stream>>>(partials, out, n_nodes);

    k4_overflow<<<4, 256, 0, stream>>>(ovf, ovf_cnt, out);
}